// Round 1
// baseline (8651.351 us; speedup 1.0000x reference)
//
#include <hip/hip_runtime.h>

// Problem constants
//   B=2048, T=96, D_IN=64, H=256, L=2, K=20
// Persistent kernel: 64 blocks x 512 threads (8 waves), each block owns 32 batch rows
// for all 96 timesteps. Weights prepacked to bf16 in d_ws by prep kernel:
//   W0cat [1024][320]  = [W_ih0 | W_hh0]   (A = [x_t | h0])
//   W1cat [1024][512]  = [W_ih1 | W_hh1]   (A = [h0n | h1])
//   Wp    [32][512]    = [W_pb ; W_pg ; 0-pad]  (A = hp interleaved h0n/h1n)
//   bias0/bias1 f32[1024] = b_ih + b_hh

typedef __attribute__((ext_vector_type(8))) short short8v;   // 8 x bf16 (4 VGPRs)
typedef __attribute__((ext_vector_type(4))) float f32x4;

static __device__ __forceinline__ unsigned short f2bf(float f) {
  unsigned int u = __float_as_uint(f);
  u += 0x7fffu + ((u >> 16) & 1u);   // round-to-nearest-even
  return (unsigned short)(u >> 16);
}
static __device__ __forceinline__ float sigf(float x) { return 1.f / (1.f + __expf(-x)); }
static __device__ __forceinline__ float tanhfast(float x) {
  float xc = fminf(fmaxf(x, -15.f), 15.f);
  float e = __expf(2.f * xc);
  return (e - 1.f) / (e + 1.f);
}
static __device__ __forceinline__ float softplusf(float x) {
  // == jax.nn.softplus (logaddexp(x,0)), stable both sides
  return (x > 0.f) ? (x + log1pf(expf(-x))) : log1pf(expf(x));
}

// ---------------- prep: pack weights to bf16, sum biases ----------------
__global__ void prep_kernel(const float* __restrict__ Wih0, const float* __restrict__ Whh0,
                            const float* __restrict__ Wih1, const float* __restrict__ Whh1,
                            const float* __restrict__ bih0, const float* __restrict__ bhh0,
                            const float* __restrict__ bih1, const float* __restrict__ bhh1,
                            const float* __restrict__ Wpb,  const float* __restrict__ Wpg,
                            unsigned short* __restrict__ W0, unsigned short* __restrict__ W1,
                            unsigned short* __restrict__ Wp,
                            float* __restrict__ bias0, float* __restrict__ bias1) {
  int i = blockIdx.x * 256 + threadIdx.x;
  if (i < 1024 * 320) {
    int n = i / 320, k = i - n * 320;
    float v = (k < 64) ? Wih0[n * 64 + k] : Whh0[n * 256 + (k - 64)];
    W0[i] = f2bf(v);
    return;
  }
  i -= 1024 * 320;
  if (i < 1024 * 512) {
    int n = i >> 9, k = i & 511;
    float v = (k < 256) ? Wih1[n * 256 + k] : Whh1[n * 256 + (k - 256)];
    W1[i] = f2bf(v);
    return;
  }
  i -= 1024 * 512;
  if (i < 32 * 512) {
    int r = i >> 9, k = i & 511;
    float v = (r == 0) ? Wpb[k] : (r <= 20 ? Wpg[(r - 1) * 512 + k] : 0.f);
    Wp[i] = f2bf(v);
    return;
  }
  i -= 32 * 512;
  if (i < 1024) { bias0[i] = bih0[i] + bhh0[i]; return; }
  i -= 1024;
  if (i < 1024) { bias1[i] = bih1[i] + bhh1[i]; return; }
}

// ---------------- main persistent kernel ----------------
__global__ __launch_bounds__(512, 2) void lstm_crps_kernel(
    const float* __restrict__ X,      // [2048,96,64]
    const float* __restrict__ Y,      // [2048,96]
    const unsigned short* __restrict__ W0,   // [1024][320] bf16
    const unsigned short* __restrict__ W1,   // [1024][512] bf16
    const unsigned short* __restrict__ Wp,   // [32][512] bf16
    const float* __restrict__ bias0, const float* __restrict__ bias1,
    const float* __restrict__ bpb, const float* __restrict__ bpg,
    float* __restrict__ out) {
  // LDS tiles. Row strides padded to odd multiples of 16B to spread banks.
  __shared__ unsigned short A0[32][328];   // [x_t(64) | h0(256)] bf16
  __shared__ unsigned short A1[32][264];   // h1 bf16
  __shared__ unsigned short HPs[32][520];  // hp interleaved: [2j]=h0n, [2j+1]=h1n
  __shared__ float PJ[32][33];             // proj output (beta0 | gamma[20] | pad)
  __shared__ float ytile[32];

  const int tid = threadIdx.x;
  const int w  = tid >> 6;    // wave 0..7
  const int l  = tid & 63;
  const int lr = l & 15;      // col-in-tile / A-row
  const int lg = l >> 4;      // K-group
  const int b0 = blockIdx.x * 32;

  // zero h regions (x region overwritten every step; extra zeroing harmless)
  for (int i = tid; i < 32 * 328 / 2; i += 512) ((int*)A0)[i] = 0;
  for (int i = tid; i < 32 * 264 / 2; i += 512) ((int*)A1)[i] = 0;

  // per-thread gate column indices: j = 16w + 128*jt + lr
  const int jcA = 16 * w + lr;          // jt = 0
  const int jcB = 16 * w + 128 + lr;    // jt = 1
  float bz0[4][2], bz1[4][2];
#pragma unroll
  for (int g = 0; g < 4; ++g) {
    bz0[g][0] = bias0[g * 256 + jcA]; bz0[g][1] = bias0[g * 256 + jcB];
    bz1[g][0] = bias1[g * 256 + jcA]; bz1[g][1] = bias1[g * 256 + jcB];
  }
  float c0s[2][2][4] = {};   // [m][jt][r]
  float c1s[2][2][4] = {};
  float lossacc = 0.f;
  const float bpbv = bpb[0];

  __syncthreads();

  for (int t = 0; t < 96; ++t) {
    // ---- load x_t tile (32x64 f32 -> bf16) + labels
    {
      int row = tid >> 4, seg = tid & 15;
      const float4 v = *(const float4*)(X + (((size_t)(b0 + row)) * 96 + t) * 64 + seg * 4);
      unsigned short* p = &A0[row][seg * 4];
      p[0] = f2bf(v.x); p[1] = f2bf(v.y); p[2] = f2bf(v.z); p[3] = f2bf(v.w);
      if (tid < 32) ytile[tid] = Y[(size_t)(b0 + tid) * 96 + t];
    }
    __syncthreads();

    // ---- GEMM0: z0[32][1024] = [x|h0] @ W0^T ; wave w owns N-tiles w+8q
    f32x4 acc[2][8];
#pragma unroll
    for (int m = 0; m < 2; ++m)
#pragma unroll
      for (int q = 0; q < 8; ++q) { f32x4 z = {0.f, 0.f, 0.f, 0.f}; acc[m][q] = z; }

#pragma unroll
    for (int kk = 0; kk < 10; ++kk) {
      short8v a0 = *(const short8v*)&A0[lr][kk * 32 + lg * 8];
      short8v a1 = *(const short8v*)&A0[16 + lr][kk * 32 + lg * 8];
#pragma unroll
      for (int q = 0; q < 8; ++q) {
        int g = q >> 1, jt = q & 1;
        int n = g * 256 + 16 * w + 128 * jt + lr;
        short8v bf = *(const short8v*)&W0[(size_t)n * 320 + kk * 32 + lg * 8];
        acc[0][q] = __builtin_amdgcn_mfma_f32_16x16x32_bf16(a0, bf, acc[0][q], 0, 0, 0);
        acc[1][q] = __builtin_amdgcn_mfma_f32_16x16x32_bf16(a1, bf, acc[1][q], 0, 0, 0);
      }
    }
    __syncthreads();   // all A0 h-region reads done before overwrite

    // ---- LSTM cell 0 (pure registers; c in VGPRs)
#pragma unroll
    for (int m = 0; m < 2; ++m)
#pragma unroll
      for (int jt = 0; jt < 2; ++jt)
#pragma unroll
        for (int r = 0; r < 4; ++r) {
          int row = m * 16 + lg * 4 + r;
          int j = 16 * w + 128 * jt + lr;
          float zi = acc[m][0 + jt][r] + bz0[0][jt];
          float zf = acc[m][2 + jt][r] + bz0[1][jt];
          float zg = acc[m][4 + jt][r] + bz0[2][jt];
          float zo = acc[m][6 + jt][r] + bz0[3][jt];
          float cn = sigf(zf) * c0s[m][jt][r] + sigf(zi) * tanhfast(zg);
          c0s[m][jt][r] = cn;
          float hn = sigf(zo) * tanhfast(cn);
          unsigned short hb = f2bf(hn);
          A0[row][64 + j] = hb;     // h0 state for next step + layer1 input
          HPs[row][2 * j] = hb;     // hp even cols
        }
    __syncthreads();   // h0n visible

    // ---- GEMM1: z1 = [h0n | h1] @ W1^T
#pragma unroll
    for (int m = 0; m < 2; ++m)
#pragma unroll
      for (int q = 0; q < 8; ++q) { f32x4 z = {0.f, 0.f, 0.f, 0.f}; acc[m][q] = z; }

#pragma unroll
    for (int kk = 0; kk < 16; ++kk) {
      short8v a0, a1;
      if (kk < 8) {
        a0 = *(const short8v*)&A0[lr][64 + kk * 32 + lg * 8];
        a1 = *(const short8v*)&A0[16 + lr][64 + kk * 32 + lg * 8];
      } else {
        a0 = *(const short8v*)&A1[lr][(kk - 8) * 32 + lg * 8];
        a1 = *(const short8v*)&A1[16 + lr][(kk - 8) * 32 + lg * 8];
      }
#pragma unroll
      for (int q = 0; q < 8; ++q) {
        int g = q >> 1, jt = q & 1;
        int n = g * 256 + 16 * w + 128 * jt + lr;
        short8v bf = *(const short8v*)&W1[(size_t)n * 512 + kk * 32 + lg * 8];
        acc[0][q] = __builtin_amdgcn_mfma_f32_16x16x32_bf16(a0, bf, acc[0][q], 0, 0, 0);
        acc[1][q] = __builtin_amdgcn_mfma_f32_16x16x32_bf16(a1, bf, acc[1][q], 0, 0, 0);
      }
    }
    __syncthreads();   // A1 reads done before overwrite

    // ---- LSTM cell 1
#pragma unroll
    for (int m = 0; m < 2; ++m)
#pragma unroll
      for (int jt = 0; jt < 2; ++jt)
#pragma unroll
        for (int r = 0; r < 4; ++r) {
          int row = m * 16 + lg * 4 + r;
          int j = 16 * w + 128 * jt + lr;
          float zi = acc[m][0 + jt][r] + bz1[0][jt];
          float zf = acc[m][2 + jt][r] + bz1[1][jt];
          float zg = acc[m][4 + jt][r] + bz1[2][jt];
          float zo = acc[m][6 + jt][r] + bz1[3][jt];
          float cn = sigf(zf) * c1s[m][jt][r] + sigf(zi) * tanhfast(zg);
          c1s[m][jt][r] = cn;
          float hn = sigf(zo) * tanhfast(cn);
          unsigned short hb = f2bf(hn);
          A1[row][j] = hb;            // h1 state for next step
          HPs[row][2 * j + 1] = hb;   // hp odd cols
        }
    __syncthreads();   // HP complete

    // ---- projection: PJ[32][21] = hp @ Wp^T (waves 0..3, one 16x16 tile each)
    if (w < 4) {
      int mm = w >> 1, np = w & 1;
      f32x4 ap = {0.f, 0.f, 0.f, 0.f};
#pragma unroll
      for (int kk = 0; kk < 16; ++kk) {
        short8v a = *(const short8v*)&HPs[mm * 16 + lr][kk * 32 + lg * 8];
        short8v bf = *(const short8v*)&Wp[(size_t)(np * 16 + lr) * 512 + kk * 32 + lg * 8];
        ap = __builtin_amdgcn_mfma_f32_16x16x32_bf16(a, bf, ap, 0, 0, 0);
      }
#pragma unroll
      for (int r = 0; r < 4; ++r)
        PJ[mm * 16 + lg * 4 + r][np * 16 + lr] = ap[r];
    }
    __syncthreads();

    // ---- CRPS spline loss: wave 0, one lane per batch row
    if (w == 0 && l < 32) {
      const int row = l;
      const float y = ytile[row];
      float beta0 = softplusf(PJ[row][0] + bpbv);
      float gam[20];
#pragma unroll
      for (int k2 = 0; k2 < 20; ++k2) gam[k2] = softplusf(PJ[row][1 + k2] + bpg[k2]);
      float braw[20];
      braw[0] = (gam[0] - beta0) * 10.f;
#pragma unroll
      for (int i2 = 1; i2 < 20; ++i2) braw[i2] = (gam[i2] - gam[i2 - 1]) * 10.f;
      float bb[20];
      bb[0] = braw[0];
#pragma unroll
      for (int i2 = 1; i2 < 20; ++i2) bb[i2] = braw[i2] - braw[i2 - 1];
      float ssum = 0.f;
#pragma unroll
      for (int i2 = 0; i2 < 19; ++i2) ssum += bb[i2];
      bb[19] = gam[19] - ssum;
      // F at interior knots (kn coefficients are compile-time constants)
      float F[20];
#pragma unroll
      for (int i2 = 0; i2 < 20; ++i2) {
        float a = (float)(i2 + 1) * 0.05f * beta0;
#pragma unroll
        for (int j2 = 0; j2 <= i2; ++j2) {
          float kn = (float)(i2 + 1 - j2) * 0.05f;
          a += kn * kn * bb[j2];
        }
        F[i2] = a;
      }
      float Aq = 0.f, Bk = 0.f, Ck = 0.f, crps3 = 0.f;
      float best = 1e30f; int amin = 0;
#pragma unroll
      for (int i2 = 0; i2 < 20; ++i2) {
        float knot = (i2 == 0) ? 0.f : F[i2 - 1];
        float d = y - knot;
        float ad = fabsf(d);
        if (ad < best) { best = ad; amin = i2; }   // first-occurrence argmin
        float alf = (d > 0.f) ? 1.f : 0.f;
        float ks = (float)i2 * 0.05f;
        float ab = alf * bb[i2];
        Aq += ab; Bk += ab * ks; Ck += ab * ks * ks;
        float om = 1.f - ks; float om2 = om * om;
        crps3 += bb[i2] * (1.f / 6.f) * om2 * om2;
      }
      float Bc = beta0 - 2.f * Bk;
      float Cc = Ck - y;
      float disc = Bc * Bc - 4.f * Aq * Cc;
      bool az = (Aq == 0.f);
      bool qs = (!az) && (disc >= 0.f);
      float alpha;
      if (qs)      alpha = (-Bc + sqrtf(disc)) / (2.f * Aq);
      else if (az) alpha = -Cc / ((Bc == 0.f) ? 1.f : Bc);
      else         alpha = (float)amin * 0.05f;
      float crps4 = 0.f;
#pragma unroll
      for (int i2 = 0; i2 < 20; ++i2) {
        float knot = (i2 == 0) ? 0.f : F[i2 - 1];
        float alf = ((y - knot) > 0.f) ? 1.f : 0.f;
        float am = alpha - (float)i2 * 0.05f;
        crps4 += alf * (2.f / 3.f) * bb[i2] * am * am * am;
      }
      lossacc += (-y * (1.f - 2.f * alpha) + beta0 * (1.f / 3.f - alpha * alpha) + crps3 - crps4);
    }
    __syncthreads();   // protect ytile/PJ before next step overwrites
  }

  // block reduction (only wave 0 lanes 0..31 hold nonzero)
  if (w == 0) {
#pragma unroll
    for (int off = 32; off > 0; off >>= 1) lossacc += __shfl_down(lossacc, off, 64);
    if (l == 0) atomicAdd(out, lossacc * (1.f / 2048.f));
  }
}

extern "C" void kernel_launch(void* const* d_in, const int* in_sizes, int n_in,
                              void* d_out, int out_size, void* d_ws, size_t ws_size,
                              hipStream_t stream) {
  const float* X    = (const float*)d_in[0];
  const float* Y    = (const float*)d_in[1];
  const float* Wih0 = (const float*)d_in[2];
  const float* Whh0 = (const float*)d_in[3];
  const float* Wih1 = (const float*)d_in[4];
  const float* Whh1 = (const float*)d_in[5];
  const float* bih0 = (const float*)d_in[6];
  const float* bhh0 = (const float*)d_in[7];
  const float* bih1 = (const float*)d_in[8];
  const float* bhh1 = (const float*)d_in[9];
  const float* Wpb  = (const float*)d_in[10];
  const float* bpb  = (const float*)d_in[11];
  const float* Wpg  = (const float*)d_in[12];
  const float* bpg  = (const float*)d_in[13];

  char* ws = (char*)d_ws;
  unsigned short* W0 = (unsigned short*)(ws);                 // 1024*320*2 = 655360
  unsigned short* W1 = (unsigned short*)(ws + 655360);        // 1024*512*2 = 1048576
  unsigned short* Wp = (unsigned short*)(ws + 1703936);       // 32*512*2   = 32768
  float* bias0 = (float*)(ws + 1736704);                      // 4096
  float* bias1 = (float*)(ws + 1740800);                      // 4096

  hipMemsetAsync(d_out, 0, sizeof(float), stream);
  prep_kernel<<<3400, 256, 0, stream>>>(Wih0, Whh0, Wih1, Whh1, bih0, bhh0, bih1, bhh1,
                                        Wpb, Wpg, W0, W1, Wp, bias0, bias1);
  lstm_crps_kernel<<<64, 512, 0, stream>>>(X, Y, W0, W1, Wp, bias0, bias1, bpb, bpg,
                                           (float*)d_out);
}

// Round 2
// 7238.152 us; speedup vs baseline: 1.1952x; 1.1952x over previous
//
#include <hip/hip_runtime.h>

// B=2048, T=96, D_IN=64, H=256, L=2, K=20
// Persistent kernel: 64 blocks x 1024 threads (16 waves, 4/SIMD), each block owns
// 32 batch rows for all 96 timesteps. Wave w owns j-columns 128*(w>>3)+16*(w&7)+lr
// (all 4 gates per column -> LSTM cell is pure register math; c stays in VGPRs).
// Weights prepacked bf16 in d_ws:
//   W0cat [1024][320] = [W_ih0 | W_hh0]   (A = [x_t | h0])
//   W1cat [1024][512] = [W_ih1 | W_hh1]   (A = [h0n | h1])
//   Wp    [32][512]   = [W_pb ; W_pg ; 0] (A = hp interleaved h0n/h1n)
//   bias0/bias1 f32[1024] = b_ih + b_hh

typedef __attribute__((ext_vector_type(8))) short short8v;   // 8 x bf16 (4 VGPRs)
typedef __attribute__((ext_vector_type(4))) float f32x4;

static __device__ __forceinline__ unsigned short f2bf(float f) {
  unsigned int u = __float_as_uint(f);
  u += 0x7fffu + ((u >> 16) & 1u);   // round-to-nearest-even
  return (unsigned short)(u >> 16);
}
static __device__ __forceinline__ float sigf(float x) { return 1.f / (1.f + __expf(-x)); }
static __device__ __forceinline__ float tanhfast(float x) {
  float xc = fminf(fmaxf(x, -15.f), 15.f);
  float e = __expf(2.f * xc);
  return (e - 1.f) / (e + 1.f);
}
static __device__ __forceinline__ float softplusf(float x) {
  return (x > 0.f) ? (x + log1pf(expf(-x))) : log1pf(expf(x));
}

// ---------------- prep: pack weights to bf16, sum biases ----------------
__global__ void prep_kernel(const float* __restrict__ Wih0, const float* __restrict__ Whh0,
                            const float* __restrict__ Wih1, const float* __restrict__ Whh1,
                            const float* __restrict__ bih0, const float* __restrict__ bhh0,
                            const float* __restrict__ bih1, const float* __restrict__ bhh1,
                            const float* __restrict__ Wpb,  const float* __restrict__ Wpg,
                            unsigned short* __restrict__ W0, unsigned short* __restrict__ W1,
                            unsigned short* __restrict__ Wp,
                            float* __restrict__ bias0, float* __restrict__ bias1) {
  int i = blockIdx.x * 256 + threadIdx.x;
  if (i < 1024 * 320) {
    int n = i / 320, k = i - n * 320;
    float v = (k < 64) ? Wih0[n * 64 + k] : Whh0[n * 256 + (k - 64)];
    W0[i] = f2bf(v);
    return;
  }
  i -= 1024 * 320;
  if (i < 1024 * 512) {
    int n = i >> 9, k = i & 511;
    float v = (k < 256) ? Wih1[n * 256 + k] : Whh1[n * 256 + (k - 256)];
    W1[i] = f2bf(v);
    return;
  }
  i -= 1024 * 512;
  if (i < 32 * 512) {
    int r = i >> 9, k = i & 511;
    float v = (r == 0) ? Wpb[k] : (r <= 20 ? Wpg[(r - 1) * 512 + k] : 0.f);
    Wp[i] = f2bf(v);
    return;
  }
  i -= 32 * 512;
  if (i < 1024) { bias0[i] = bih0[i] + bhh0[i]; return; }
  i -= 1024;
  if (i < 1024) { bias1[i] = bih1[i] + bhh1[i]; return; }
}

// ---------------- main persistent kernel ----------------
__global__ __launch_bounds__(1024, 4) void lstm_crps_kernel(
    const float* __restrict__ X,      // [2048,96,64]
    const float* __restrict__ Y,      // [2048,96]
    const unsigned short* __restrict__ W0,   // [1024][320] bf16
    const unsigned short* __restrict__ W1,   // [1024][512] bf16
    const unsigned short* __restrict__ Wp,   // [32][512] bf16
    const float* __restrict__ bias0, const float* __restrict__ bias1,
    const float* __restrict__ bpb, const float* __restrict__ bpg,
    float* __restrict__ out) {
  __shared__ unsigned short A0[32][328];   // [x_t(64) | h0(256)] bf16
  __shared__ unsigned short A1[32][264];   // h1 bf16
  __shared__ unsigned short HPs[32][520];  // hp interleaved: [2j]=h0n, [2j+1]=h1n
  __shared__ float PJ[32][33];             // proj output (beta0 | gamma[20] | pad)
  __shared__ float ytile[32];
  __shared__ float bpgs[20];

  const int tid = threadIdx.x;
  const int w  = tid >> 6;    // wave 0..15
  const int l  = tid & 63;
  const int lr = l & 15;      // A-row / B-row (n) low bits / D-col
  const int lg = l >> 4;      // K-group / D-row group
  const int b0 = blockIdx.x * 32;

  const int jt = w >> 3;            // which 128-col half
  const int wq = w & 7;             // 16-col tile within half
  const int joff = 128 * jt + 16 * wq + lr;   // this thread's j column

  // zero h regions
  for (int i = tid; i < 32 * 328 / 2; i += 1024) ((int*)A0)[i] = 0;
  for (int i = tid; i < 32 * 264 / 2; i += 1024) ((int*)A1)[i] = 0;
  if (tid < 20) bpgs[tid] = bpg[tid];

  // per-gate weight row bases (element offsets) and biases for this j
  int rb0[4], rb1[4];
  float bz0[4], bz1[4];
#pragma unroll
  for (int g = 0; g < 4; ++g) {
    int n = g * 256 + joff;
    rb0[g] = n * 320;
    rb1[g] = n * 512;
    bz0[g] = bias0[n];
    bz1[g] = bias1[n];
  }
  float c0s[2][4] = {};   // [m][r]
  float c1s[2][4] = {};
  float lossacc = 0.f;
  const float bpbv = bpb[0];

  __syncthreads();

  for (int t = 0; t < 96; ++t) {
    // ---- load x_t tile (32x64 f32 -> bf16) + labels
    {
      int row = tid >> 5, seg = tid & 31;
      const float2 v = *(const float2*)(X + (((size_t)(b0 + row)) * 96 + t) * 64 + seg * 2);
      unsigned short* p = &A0[row][seg * 2];
      p[0] = f2bf(v.x); p[1] = f2bf(v.y);
      if (tid < 32) ytile[tid] = Y[(size_t)(b0 + tid) * 96 + t];
    }
    __syncthreads();

    // ---- GEMM0: z0[32][1024] = [x|h0] @ W0^T
    f32x4 acc[2][4];
#pragma unroll
    for (int m = 0; m < 2; ++m)
#pragma unroll
      for (int g = 0; g < 4; ++g) { f32x4 z = {0.f, 0.f, 0.f, 0.f}; acc[m][g] = z; }

#pragma unroll
    for (int kk = 0; kk < 10; ++kk) {
      const int kof = kk * 32 + lg * 8;
      short8v a0 = *(const short8v*)&A0[lr][kof];
      short8v a1 = *(const short8v*)&A0[16 + lr][kof];
#pragma unroll
      for (int g = 0; g < 4; ++g) {
        short8v bf = *(const short8v*)&W0[rb0[g] + kof];
        acc[0][g] = __builtin_amdgcn_mfma_f32_16x16x32_bf16(a0, bf, acc[0][g], 0, 0, 0);
        acc[1][g] = __builtin_amdgcn_mfma_f32_16x16x32_bf16(a1, bf, acc[1][g], 0, 0, 0);
      }
    }
    __syncthreads();   // all A0 h-region reads done before overwrite

    // ---- LSTM cell 0 (registers only; c in VGPRs)
#pragma unroll
    for (int m = 0; m < 2; ++m)
#pragma unroll
      for (int r = 0; r < 4; ++r) {
        int row = m * 16 + lg * 4 + r;
        float zi = acc[m][0][r] + bz0[0];
        float zf = acc[m][1][r] + bz0[1];
        float zg = acc[m][2][r] + bz0[2];
        float zo = acc[m][3][r] + bz0[3];
        float cn = sigf(zf) * c0s[m][r] + sigf(zi) * tanhfast(zg);
        c0s[m][r] = cn;
        float hn = sigf(zo) * tanhfast(cn);
        unsigned short hb = f2bf(hn);
        A0[row][64 + joff] = hb;   // h0 state for next step + layer1 input
        HPs[row][2 * joff] = hb;   // hp even cols
      }
    __syncthreads();   // h0n visible

    // ---- GEMM1: z1 = [h0n | h1] @ W1^T
#pragma unroll
    for (int m = 0; m < 2; ++m)
#pragma unroll
      for (int g = 0; g < 4; ++g) { f32x4 z = {0.f, 0.f, 0.f, 0.f}; acc[m][g] = z; }

#pragma unroll
    for (int kk = 0; kk < 16; ++kk) {
      const int kof = kk * 32 + lg * 8;
      short8v a0, a1;
      if (kk < 8) {
        a0 = *(const short8v*)&A0[lr][64 + kof];
        a1 = *(const short8v*)&A0[16 + lr][64 + kof];
      } else {
        a0 = *(const short8v*)&A1[lr][kof - 256];
        a1 = *(const short8v*)&A1[16 + lr][kof - 256];
      }
#pragma unroll
      for (int g = 0; g < 4; ++g) {
        short8v bf = *(const short8v*)&W1[rb1[g] + kof];
        acc[0][g] = __builtin_amdgcn_mfma_f32_16x16x32_bf16(a0, bf, acc[0][g], 0, 0, 0);
        acc[1][g] = __builtin_amdgcn_mfma_f32_16x16x32_bf16(a1, bf, acc[1][g], 0, 0, 0);
      }
    }
    __syncthreads();   // A1 reads done before overwrite

    // ---- LSTM cell 1
#pragma unroll
    for (int m = 0; m < 2; ++m)
#pragma unroll
      for (int r = 0; r < 4; ++r) {
        int row = m * 16 + lg * 4 + r;
        float zi = acc[m][0][r] + bz1[0];
        float zf = acc[m][1][r] + bz1[1];
        float zg = acc[m][2][r] + bz1[2];
        float zo = acc[m][3][r] + bz1[3];
        float cn = sigf(zf) * c1s[m][r] + sigf(zi) * tanhfast(zg);
        c1s[m][r] = cn;
        float hn = sigf(zo) * tanhfast(cn);
        unsigned short hb = f2bf(hn);
        A1[row][joff] = hb;            // h1 state for next step
        HPs[row][2 * joff + 1] = hb;   // hp odd cols
      }
    __syncthreads();   // HP complete

    // ---- projection: PJ[32][21] = hp @ Wp^T (waves 0..3)
    if (w < 4) {
      int mm = w >> 1, np = w & 1;
      f32x4 ap = {0.f, 0.f, 0.f, 0.f};
#pragma unroll
      for (int kk = 0; kk < 16; ++kk) {
        short8v a = *(const short8v*)&HPs[mm * 16 + lr][kk * 32 + lg * 8];
        short8v bf = *(const short8v*)&Wp[(size_t)(np * 16 + lr) * 512 + kk * 32 + lg * 8];
        ap = __builtin_amdgcn_mfma_f32_16x16x32_bf16(a, bf, ap, 0, 0, 0);
      }
#pragma unroll
      for (int r = 0; r < 4; ++r)
        PJ[mm * 16 + lg * 4 + r][np * 16 + lr] = ap[r];
    }
    __syncthreads();   // PJ visible to wave 0

    // ---- CRPS spline loss: wave 0, one lane per batch row
    if (w == 0 && l < 32) {
      const int row = l;
      const float y = ytile[row];
      float beta0 = softplusf(PJ[row][0] + bpbv);
      float gam[20];
#pragma unroll
      for (int k2 = 0; k2 < 20; ++k2) gam[k2] = softplusf(PJ[row][1 + k2] + bpgs[k2]);
      float braw[20];
      braw[0] = (gam[0] - beta0) * 10.f;
#pragma unroll
      for (int i2 = 1; i2 < 20; ++i2) braw[i2] = (gam[i2] - gam[i2 - 1]) * 10.f;
      float bb[20];
      bb[0] = braw[0];
#pragma unroll
      for (int i2 = 1; i2 < 20; ++i2) bb[i2] = braw[i2] - braw[i2 - 1];
      float ssum = 0.f;
#pragma unroll
      for (int i2 = 0; i2 < 19; ++i2) ssum += bb[i2];
      bb[19] = gam[19] - ssum;
      float F[20];
#pragma unroll
      for (int i2 = 0; i2 < 20; ++i2) {
        float a = (float)(i2 + 1) * 0.05f * beta0;
#pragma unroll
        for (int j2 = 0; j2 <= i2; ++j2) {
          float kn = (float)(i2 + 1 - j2) * 0.05f;
          a += kn * kn * bb[j2];
        }
        F[i2] = a;
      }
      float Aq = 0.f, Bk = 0.f, Ck = 0.f, crps3 = 0.f;
      float best = 1e30f; int amin = 0;
#pragma unroll
      for (int i2 = 0; i2 < 20; ++i2) {
        float knot = (i2 == 0) ? 0.f : F[i2 - 1];
        float d = y - knot;
        float ad = fabsf(d);
        if (ad < best) { best = ad; amin = i2; }
        float alf = (d > 0.f) ? 1.f : 0.f;
        float ks = (float)i2 * 0.05f;
        float ab = alf * bb[i2];
        Aq += ab; Bk += ab * ks; Ck += ab * ks * ks;
        float om = 1.f - ks; float om2 = om * om;
        crps3 += bb[i2] * (1.f / 6.f) * om2 * om2;
      }
      float Bc = beta0 - 2.f * Bk;
      float Cc = Ck - y;
      float disc = Bc * Bc - 4.f * Aq * Cc;
      bool az = (Aq == 0.f);
      bool qs = (!az) && (disc >= 0.f);
      float alpha;
      if (qs)      alpha = (-Bc + sqrtf(disc)) / (2.f * Aq);
      else if (az) alpha = -Cc / ((Bc == 0.f) ? 1.f : Bc);
      else         alpha = (float)amin * 0.05f;
      float crps4 = 0.f;
#pragma unroll
      for (int i2 = 0; i2 < 20; ++i2) {
        float knot = (i2 == 0) ? 0.f : F[i2 - 1];
        float alf = ((y - knot) > 0.f) ? 1.f : 0.f;
        float am = alpha - (float)i2 * 0.05f;
        crps4 += alf * (2.f / 3.f) * bb[i2] * am * am * am;
      }
      lossacc += (-y * (1.f - 2.f * alpha) + beta0 * (1.f / 3.f - alpha * alpha) + crps3 - crps4);
    }
    // NOTE: no barrier here — wave 0 writes ytile itself next iter (same-wave order),
    // and PJ(t+1) writes are ordered after 5 intervening barriers.
  }

  // block reduction (only wave 0 lanes 0..31 hold nonzero)
  if (w == 0) {
#pragma unroll
    for (int off = 32; off > 0; off >>= 1) lossacc += __shfl_down(lossacc, off, 64);
    if (l == 0) atomicAdd(out, lossacc * (1.f / 2048.f));
  }
}

extern "C" void kernel_launch(void* const* d_in, const int* in_sizes, int n_in,
                              void* d_out, int out_size, void* d_ws, size_t ws_size,
                              hipStream_t stream) {
  const float* X    = (const float*)d_in[0];
  const float* Y    = (const float*)d_in[1];
  const float* Wih0 = (const float*)d_in[2];
  const float* Whh0 = (const float*)d_in[3];
  const float* Wih1 = (const float*)d_in[4];
  const float* Whh1 = (const float*)d_in[5];
  const float* bih0 = (const float*)d_in[6];
  const float* bhh0 = (const float*)d_in[7];
  const float* bih1 = (const float*)d_in[8];
  const float* bhh1 = (const float*)d_in[9];
  const float* Wpb  = (const float*)d_in[10];
  const float* bpb  = (const float*)d_in[11];
  const float* Wpg  = (const float*)d_in[12];
  const float* bpg  = (const float*)d_in[13];

  char* ws = (char*)d_ws;
  unsigned short* W0 = (unsigned short*)(ws);                 // 1024*320*2 = 655360
  unsigned short* W1 = (unsigned short*)(ws + 655360);        // 1024*512*2 = 1048576
  unsigned short* Wp = (unsigned short*)(ws + 1703936);       // 32*512*2   = 32768
  float* bias0 = (float*)(ws + 1736704);                      // 4096
  float* bias1 = (float*)(ws + 1740800);                      // 4096

  hipMemsetAsync(d_out, 0, sizeof(float), stream);
  prep_kernel<<<3400, 256, 0, stream>>>(Wih0, Whh0, Wih1, Whh1, bih0, bhh0, bih1, bhh1,
                                        Wpb, Wpg, W0, W1, Wp, bias0, bias1);
  lstm_crps_kernel<<<64, 1024, 0, stream>>>(X, Y, W0, W1, Wp, bias0, bias1, bpb, bpg,
                                            (float*)d_out);
}